// Round 11
// baseline (133.578 us; speedup 1.0000x reference)
//
#include <hip/hip_runtime.h>
#include <hip/hip_bf16.h>

#define SEQ 8192
#define HD 128
#define BM 128
#define BN 64
#define NQT (SEQ / BM)   // 64
#define THREADS 512

typedef __bf16 bf16_t;
typedef __bf16 bf16x2 __attribute__((ext_vector_type(2)));
typedef __bf16 bf16x8 __attribute__((ext_vector_type(8)));
typedef float f32x4 __attribute__((ext_vector_type(4)));
typedef float f32x16 __attribute__((ext_vector_type(16)));
typedef unsigned int u32x4 __attribute__((ext_vector_type(4)));

#if __has_builtin(__builtin_amdgcn_exp2f)
__device__ inline float exp2_fast(float x) { return __builtin_amdgcn_exp2f(x); }
#else
__device__ inline float exp2_fast(float x) { return exp2f(x); }
#endif

// v_permlane32_swap_b32: a.hi32lanes <-> b.lo32lanes (one VALU op).
// Verified (R9 pass): {a',b',c',d'} after swap(a,c),swap(b,d) is exactly the
// PV A-frag / pbuf word layout the old shfl_xor+cndmask construction made.
__device__ inline void permswap32(unsigned int& a, unsigned int& b) {
#if __has_builtin(__builtin_amdgcn_permlane32_swap)
  auto r = __builtin_amdgcn_permlane32_swap(a, b, false, false);
  a = (unsigned int)r[0];
  b = (unsigned int)r[1];
#else
  asm volatile("v_permlane32_swap_b32 %0, %1" : "+v"(a), "+v"(b));
#endif
}

// async global->LDS DMA, 16 B per lane; lds dest wave-uniform, HW adds lane*16
__device__ inline void load_lds16(const void* g, void* l) {
  __builtin_amdgcn_global_load_lds(
      (const __attribute__((address_space(1))) void*)g,
      (__attribute__((address_space(3))) void*)l, 16, 0, 0);
}

// ---------------- prep ----------------
// Kb blocked: [tile T][d-chunk c 0..15][key r 0..63][8]  = K[T*64+r][c*8+j]
// VT blocked: [tile T][key-chunk kc 0..7][d 0..127][8]   = V[T*64+kc*8+j][d]
__global__ __launch_bounds__(256) void prep_kernel(const float* __restrict__ K,
                                                   const float* __restrict__ V,
                                                   bf16_t* __restrict__ Kb,
                                                   bf16_t* __restrict__ VT) {
  const int b = (int)blockIdx.x;
  const int tid = (int)threadIdx.x;
  if (b < 256) {
    // V tile: 64 keys x 64 d, staged f32 in LDS (coalesced reads)
    __shared__ float tile[64][65];
    const int T = b & 127;
    const int d0 = (b >> 7) * 64;
    const int s0 = T * 64;
    const int r = tid >> 2;          // 0..63 (key)
    const int c0 = (tid & 3) * 16;   // d offset
#pragma unroll
    for (int j4 = 0; j4 < 4; ++j4) {
      float4 x = *(const float4*)&V[(size_t)(s0 + r) * HD + d0 + c0 + j4 * 4];
      tile[r][c0 + j4 * 4 + 0] = x.x;
      tile[r][c0 + j4 * 4 + 1] = x.y;
      tile[r][c0 + j4 * 4 + 2] = x.z;
      tile[r][c0 + j4 * 4 + 3] = x.w;
    }
    __syncthreads();
    const int d_l = tid & 63;
    const int kc0 = (tid >> 6) * 2;  // 0,2,4,6
#pragma unroll
    for (int k2 = 0; k2 < 2; ++k2) {
      const int kc = kc0 + k2;
      bf16x8 wv;
#pragma unroll
      for (int j = 0; j < 8; ++j) wv[j] = (bf16_t)tile[kc * 8 + j][d_l];
      *(bf16x8*)&VT[((size_t)(T * 8 + kc) * 128 + d0 + d_l) * 8] = wv;
    }
  } else {
    // K convert: one 16B chunk per thread
    const int base = (b - 256) * 2048 + tid * 8;   // flat over 8192*128
    const int row = base >> 7;
    const int c = (base >> 3) & 15;
    const int T = row >> 6;
    const int r = row & 63;
    float4 a = *(const float4*)&K[base];
    float4 cc = *(const float4*)&K[base + 4];
    bf16x8 f;
    f[0] = (bf16_t)a.x; f[1] = (bf16_t)a.y; f[2] = (bf16_t)a.z; f[3] = (bf16_t)a.w;
    f[4] = (bf16_t)cc.x; f[5] = (bf16_t)cc.y; f[6] = (bf16_t)cc.z; f[7] = (bf16_t)cc.w;
    *(bf16x8*)&Kb[((size_t)(T * 16 + c) * 64 + r) * 8] = f;
  }
}

// ---------------- main flash-attention kernel ----------------
// R11: compose R0's register-lean g-split shape (4 waves/SIMD, 128-reg cap)
// with R5-R9's cross-tile pipeline. 8 waves, qw=w&3 (32 q-rows), g=w>>2
// (key-half). Iteration it:
//   DMA K(it+1)->kt[it+1&1], DMA V(it)->vt[it&1]   (V staggered: 2 bufs)
//   QK^T(it) (8 MFMA, key-half g) INTERLEAVED with PV(it-1) (8 MFMA,
//     reads pbuf written last iter + vt[(it-1)&1]) -- independent streams
//   lgkm-only mid-barrier (pbuf reads drained; DMA stays in flight)
//   exp/pack(it) -> permlane32_swap -> overwrite pbuf (single-buffered)
//   __syncthreads (vmcnt drain, buffer swap)
// Registers: o_acc[2](32) + qf(32) + sacc(16) + temps ~ 110 < 128 cap.
// LDS 32K kt + 32K vt + 16K pbuf = 80 KB -> 2 blocks/CU = 16 waves/CU.
__global__ __launch_bounds__(THREADS, 4) void fattn_kernel(
    const float* __restrict__ Q, const bf16_t* __restrict__ Kb,
    const bf16_t* __restrict__ VT, float* __restrict__ Opart,
    float* __restrict__ Lpart, int kshift, int nit) {
  __shared__ __align__(16) bf16_t kt2[2][16][64][8];  // 32 KB [buf][d-chunk][key][8]
  __shared__ __align__(16) bf16_t vt2[2][8][128][8];  // 32 KB [buf][key-chunk][d][8]
  __shared__ __align__(16) char pbuf[4][4][64][16];   // 16 KB [qw][key-chunk16][lane][16B]

  const int tid = (int)threadIdx.x;
  const int lane = tid & 63;
  const int w = tid >> 6;
  const int qw = w & 3;
  const int g = w >> 2;
  const int h = lane >> 5;
  const int n32 = lane & 31;

  const int qt = (int)blockIdx.x >> kshift;
  const int sp = (int)blockIdx.x & ((1 << kshift) - 1);
  const int qbase = qt * BM;
  const int tile0 = sp * nit;          // first 64-key tile index

  const float SC2 = 0.08838834764831845f * 1.4426950408889634f; // (1/sqrt(128))*log2e

  // Q B-frags (n = n32 = q-row, k-dim = d), pre-scaled
  bf16x8 qf[8];
  {
    const float* qp = Q + (size_t)(qbase + qw * 32 + n32) * HD + h * 8;
#pragma unroll
    for (int kk = 0; kk < 8; ++kk) {
      float4 a = *(const float4*)(qp + kk * 16);
      float4 b = *(const float4*)(qp + kk * 16 + 4);
      bf16x8 f;
      f[0] = (bf16_t)(a.x * SC2); f[1] = (bf16_t)(a.y * SC2);
      f[2] = (bf16_t)(a.z * SC2); f[3] = (bf16_t)(a.w * SC2);
      f[4] = (bf16_t)(b.x * SC2); f[5] = (bf16_t)(b.y * SC2);
      f[6] = (bf16_t)(b.z * SC2); f[7] = (bf16_t)(b.w * SC2);
      qf[kk] = f;
    }
  }

  f32x16 o_acc[2];
#pragma unroll
  for (int i = 0; i < 2; ++i)
#pragma unroll
    for (int e = 0; e < 16; ++e) o_acc[i][e] = 0.f;
  float l_acc = 0.f;

  const int rr0 = w * 2;   // DMA region indices rr0, rr0+1 (8 waves x 2 = 16)

// exp -> pack -> permlane32_swap -> A-layout pbuf chunk write (16 keys)
#define EXPPACK1(SACC, KK2)                                                \
  {                                                                        \
    float pf[8];                                                           \
    _Pragma("unroll")                                                      \
    for (int j = 0; j < 8; ++j) pf[j] = exp2_fast((SACC)[8 * (KK2) + j]);  \
    l_acc += ((pf[0] + pf[1]) + (pf[2] + pf[3])) +                         \
             ((pf[4] + pf[5]) + (pf[6] + pf[7]));                          \
    bf16x2 p0, p1, p2, p3;                                                 \
    p0[0] = (bf16_t)pf[0]; p0[1] = (bf16_t)pf[1];                          \
    p1[0] = (bf16_t)pf[2]; p1[1] = (bf16_t)pf[3];                          \
    p2[0] = (bf16_t)pf[4]; p2[1] = (bf16_t)pf[5];                          \
    p3[0] = (bf16_t)pf[6]; p3[1] = (bf16_t)pf[7];                          \
    unsigned int sA = __builtin_bit_cast(unsigned int, p0);                \
    unsigned int sB = __builtin_bit_cast(unsigned int, p1);                \
    unsigned int sC = __builtin_bit_cast(unsigned int, p2);                \
    unsigned int sD = __builtin_bit_cast(unsigned int, p3);                \
    permswap32(sA, sC);                                                    \
    permswap32(sB, sD);                                                    \
    u32x4 fv;                                                              \
    fv[0] = sA; fv[1] = sB; fv[2] = sC; fv[3] = sD;                        \
    *(u32x4*)&pbuf[qw][g * 2 + (KK2)][lane][0] = fv;                       \
  }

// pipelined body for iteration IT>=1. KC = IT&1 (literal). Reads kt2[KC]
// (QK), vt2[KC^1] (PV of it-1), pbuf (P of it-1); DMA K(IT+1)->kt[KC^1],
// V(IT)->vt2[KC]. QK and PV MFMA streams textually interleaved.
#define FBODY(IT, KC)                                                      \
  {                                                                        \
    const int it_ = (IT);                                                  \
    if (it_ + 1 < nit) {                                                   \
      const int ntile = tile0 + it_ + 1;                                   \
      _Pragma("unroll")                                                    \
      for (int t = 0; t < 2; ++t) {                                        \
        const int rr = rr0 + t;                                            \
        load_lds16(Kb + ((size_t)(ntile * 16 + rr) * 64 + lane) * 8,       \
                   (char*)&kt2[(KC) ^ 1][0][0][0] + rr * 1024);            \
      }                                                                    \
    }                                                                      \
    {                                                                      \
      const int vtile = tile0 + it_;                                       \
      _Pragma("unroll")                                                    \
      for (int t = 0; t < 2; ++t) {                                        \
        const int rr = rr0 + t;                                            \
        load_lds16(VT + ((size_t)(vtile * 8 + (rr >> 1)) * 128 + (rr & 1) * 64 + lane) * 8, \
                   (char*)&vt2[KC][0][0][0] + rr * 1024);                  \
      }                                                                    \
    }                                                                      \
    f32x16 sacc;                                                           \
    _Pragma("unroll")                                                      \
    for (int e = 0; e < 16; ++e) sacc[e] = 0.f;                            \
    _Pragma("unroll")                                                      \
    for (int C = 0; C < 4; ++C) {                                          \
      bf16x8 af0 = *(const bf16x8*)&kt2[KC][4 * C + h][g * 32 + n32][0];   \
      sacc = __builtin_amdgcn_mfma_f32_32x32x16_bf16(af0, qf[2 * C], sacc, 0, 0, 0); \
      bf16x8 af1 = *(const bf16x8*)&kt2[KC][4 * C + 2 + h][g * 32 + n32][0]; \
      sacc = __builtin_amdgcn_mfma_f32_32x32x16_bf16(af1, qf[2 * C + 1], sacc, 0, 0, 0); \
      bf16x8 pa = *(const bf16x8*)&pbuf[qw][C][lane][0];                   \
      bf16x8 vb0 = *(const bf16x8*)&vt2[(KC) ^ 1][C * 2 + h][g * 64 + n32][0]; \
      o_acc[0] = __builtin_amdgcn_mfma_f32_32x32x16_bf16(pa, vb0, o_acc[0], 0, 0, 0); \
      bf16x8 vb1 = *(const bf16x8*)&vt2[(KC) ^ 1][C * 2 + h][g * 64 + 32 + n32][0]; \
      o_acc[1] = __builtin_amdgcn_mfma_f32_32x32x16_bf16(pa, vb1, o_acc[1], 0, 0, 0); \
    }                                                                      \
    /* pbuf reads drained; DMA (vmcnt) stays in flight */                  \
    asm volatile("s_waitcnt lgkmcnt(0)\n\ts_barrier" ::: "memory");        \
    __builtin_amdgcn_sched_barrier(0);                                     \
    EXPPACK1(sacc, 0)                                                      \
    EXPPACK1(sacc, 1)                                                      \
    __syncthreads();  /* drains K/V DMA + pbuf writes; buffer swap */      \
  }

  // ---- prologue: DMA K(tile0)->kt[0], V(tile0)->vt[0] ----
#pragma unroll
  for (int t = 0; t < 2; ++t) {
    const int rr = rr0 + t;
    load_lds16(Kb + ((size_t)(tile0 * 16 + rr) * 64 + lane) * 8,
               (char*)&kt2[0][0][0][0] + rr * 1024);
    load_lds16(VT + ((size_t)(tile0 * 8 + (rr >> 1)) * 128 + (rr & 1) * 64 + lane) * 8,
               (char*)&vt2[0][0][0][0] + rr * 1024);
  }
  __syncthreads();

  // ---- peel it=0: DMA K(1)->kt[1]; QK(0); exp(0) -> pbuf ----
  {
    if (nit > 1) {
      const int ntile = tile0 + 1;
#pragma unroll
      for (int t = 0; t < 2; ++t) {
        const int rr = rr0 + t;
        load_lds16(Kb + ((size_t)(ntile * 16 + rr) * 64 + lane) * 8,
                   (char*)&kt2[1][0][0][0] + rr * 1024);
      }
    }
    f32x16 sacc;
#pragma unroll
    for (int e = 0; e < 16; ++e) sacc[e] = 0.f;
#pragma unroll
    for (int kk = 0; kk < 8; ++kk) {
      bf16x8 af = *(const bf16x8*)&kt2[0][2 * kk + h][g * 32 + n32][0];
      sacc = __builtin_amdgcn_mfma_f32_32x32x16_bf16(af, qf[kk], sacc, 0, 0, 0);
    }
    EXPPACK1(sacc, 0)
    EXPPACK1(sacc, 1)
    __syncthreads();
  }

  // nit is always even; bodies 1..nit-2 in pairs (KC literal by parity),
  // leftover body nit-1 (odd -> KC=1).
  for (int it = 1; it + 1 <= nit - 1; it += 2) {
    FBODY(it, 1)
    FBODY(it + 1, 0)
  }
  FBODY(nit - 1, 1)

  // ---- tail: PV(nit-1) using pbuf + vt2[(nit-1)&1] ----
  {
    const int vb_buf = (nit - 1) & 1;
#pragma unroll
    for (int C = 0; C < 4; ++C) {
      bf16x8 pa = *(const bf16x8*)&pbuf[qw][C][lane][0];
      bf16x8 vb0 = *(const bf16x8*)&vt2[vb_buf][C * 2 + h][g * 64 + n32][0];
      o_acc[0] = __builtin_amdgcn_mfma_f32_32x32x16_bf16(pa, vb0, o_acc[0], 0, 0, 0);
      bf16x8 vb1 = *(const bf16x8*)&vt2[vb_buf][C * 2 + h][g * 64 + 32 + n32][0];
      o_acc[1] = __builtin_amdgcn_mfma_f32_32x32x16_bf16(pa, vb1, o_acc[1], 0, 0, 0);
    }
  }
  __syncthreads();   // all pbuf reads done before lfb reuse below

#undef FBODY
#undef EXPPACK1

  // ---- epilogue: O block store (distinct q x d block per wave) + l combine ----
  {
    float* op = Opart + ((size_t)sp * SEQ + qbase + qw * 32) * HD + g * 64;
#pragma unroll
    for (int ot = 0; ot < 2; ++ot)
#pragma unroll
      for (int reg = 0; reg < 16; ++reg) {
        const int row = (reg & 3) + 8 * (reg >> 2) + 4 * h;
        op[row * HD + ot * 32 + n32] = o_acc[ot][reg];
      }
    float l = l_acc + __shfl_xor(l_acc, 32);   // this wave's 32 keys, per q
    float* lfb = (float*)pbuf;
    if (lane < 32) lfb[g * 128 + qw * 32 + n32] = l;
    __syncthreads();
    if (g == 0 && lane < 32)
      Lpart[(size_t)sp * SEQ + qbase + qw * 32 + n32] =
          l + lfb[128 + qw * 32 + n32];
  }
}

// ---------------- combine: out = sum_s O_s / sum_s l_s ----------------
__global__ __launch_bounds__(256) void combine_kernel(const float* __restrict__ Opart,
                                                      const float* __restrict__ Lpart,
                                                      float* __restrict__ out, int ksplit) {
  const int tid = (int)threadIdx.x;
  const int row = (int)blockIdx.x * 8 + (tid >> 5);
  const int c0 = (tid & 31) * 4;
  float lsum = 0.f;
  for (int s = 0; s < ksplit; ++s) lsum += Lpart[(size_t)s * SEQ + row];
  f32x4 acc;
#pragma unroll
  for (int e = 0; e < 4; ++e) acc[e] = 0.f;
  for (int s = 0; s < ksplit; ++s) {
    f32x4 o = *(const f32x4*)&Opart[((size_t)s * SEQ + row) * HD + c0];
#pragma unroll
    for (int e = 0; e < 4; ++e) acc[e] += o[e];
  }
  const float inv = 1.0f / lsum;
  f32x4 res;
#pragma unroll
  for (int e = 0; e < 4; ++e) res[e] = acc[e] * inv;
  *(f32x4*)&out[(size_t)row * HD + c0] = res;
}

extern "C" void kernel_launch(void* const* d_in, const int* in_sizes, int n_in,
                              void* d_out, int out_size, void* d_ws, size_t ws_size,
                              hipStream_t stream) {
  const float* Q = (const float*)d_in[0];
  const float* K = (const float*)d_in[1];
  const float* V = (const float*)d_in[2];
  float* out = (float*)d_out;

  int ksplit = 8, kshift = 3;
  while (ksplit > 1) {
    size_t need = (size_t)ksplit * SEQ * HD * 4
                + (size_t)ksplit * SEQ * 4
                + (size_t)SEQ * HD * 2 * 2;
    if (need <= ws_size) break;
    ksplit >>= 1; kshift--;
  }

  char* ws = (char*)d_ws;
  float* Opart = (float*)ws;
  float* Lpart = (float*)(ws + (size_t)ksplit * SEQ * HD * 4);
  bf16_t* Kb = (bf16_t*)(ws + (size_t)ksplit * SEQ * HD * 4 + (size_t)ksplit * SEQ * 4);
  bf16_t* VT = Kb + (size_t)SEQ * HD;

  const int nit = SEQ / (ksplit * BN);

  prep_kernel<<<768, 256, 0, stream>>>(K, V, Kb, VT);
  fattn_kernel<<<NQT * ksplit, THREADS, 0, stream>>>(Q, Kb, VT, Opart, Lpart, kshift, nit);
  combine_kernel<<<SEQ / 8, 256, 0, stream>>>(Opart, Lpart, out, ksplit);
}

// Round 12
// 110.745 us; speedup vs baseline: 1.2062x; 1.2062x over previous
//
#include <hip/hip_runtime.h>
#include <hip/hip_bf16.h>

#define SEQ 8192
#define HD 128
#define BM 256
#define BN 64
#define NQT (SEQ / BM)   // 32
#define THREADS 512

typedef __bf16 bf16_t;
typedef __bf16 bf16x2 __attribute__((ext_vector_type(2)));
typedef __bf16 bf16x8 __attribute__((ext_vector_type(8)));
typedef float f32x4 __attribute__((ext_vector_type(4)));
typedef float f32x16 __attribute__((ext_vector_type(16)));
typedef unsigned int u32x4 __attribute__((ext_vector_type(4)));

#if __has_builtin(__builtin_amdgcn_exp2f)
__device__ inline float exp2_fast(float x) { return __builtin_amdgcn_exp2f(x); }
#else
__device__ inline float exp2_fast(float x) { return exp2f(x); }
#endif

// v_permlane32_swap_b32: a.hi32lanes <-> b.lo32lanes (one VALU op).
// Mapping verified by R9 pass.
__device__ inline void permswap32(unsigned int& a, unsigned int& b) {
#if __has_builtin(__builtin_amdgcn_permlane32_swap)
  auto r = __builtin_amdgcn_permlane32_swap(a, b, false, false);
  a = (unsigned int)r[0];
  b = (unsigned int)r[1];
#else
  asm volatile("v_permlane32_swap_b32 %0, %1" : "+v"(a), "+v"(b));
#endif
}

// async global->LDS DMA, 16 B per lane; lds dest wave-uniform, HW adds lane*16
__device__ inline void load_lds16(const void* g, void* l) {
  __builtin_amdgcn_global_load_lds(
      (const __attribute__((address_space(1))) void*)g,
      (__attribute__((address_space(3))) void*)l, 16, 0, 0);
}

// Counted barrier (T4): leave the N newest vmem ops in flight; FIFO vmcnt
// semantics force all older loads/DMA complete. lgkmcnt(0) drains ds reads
// (cross-wave WAR safety before DMA overwrites). sched_barrier per rule 18.
#define BARRIER(N)                                                         \
  do {                                                                     \
    asm volatile("s_waitcnt vmcnt(" #N ") lgkmcnt(0)\n\ts_barrier" ::: "memory"); \
    __builtin_amdgcn_sched_barrier(0);                                     \
  } while (0)

// ---------------- prep ----------------
// Kb blocked: [tile T][d-chunk c 0..15][key r 0..63][8]  = K[T*64+r][c*8+j]
// VT blocked: [tile T][key-chunk kc 0..7][d 0..127][8]   = V[T*64+kc*8+j][d]
__global__ __launch_bounds__(256) void prep_kernel(const float* __restrict__ K,
                                                   const float* __restrict__ V,
                                                   bf16_t* __restrict__ Kb,
                                                   bf16_t* __restrict__ VT) {
  const int b = (int)blockIdx.x;
  const int tid = (int)threadIdx.x;
  if (b < 256) {
    // V tile: 64 keys x 64 d, staged f32 in LDS (coalesced reads)
    __shared__ float tile[64][65];
    const int T = b & 127;
    const int d0 = (b >> 7) * 64;
    const int s0 = T * 64;
    const int r = tid >> 2;          // 0..63 (key)
    const int c0 = (tid & 3) * 16;   // d offset
#pragma unroll
    for (int j4 = 0; j4 < 4; ++j4) {
      float4 x = *(const float4*)&V[(size_t)(s0 + r) * HD + d0 + c0 + j4 * 4];
      tile[r][c0 + j4 * 4 + 0] = x.x;
      tile[r][c0 + j4 * 4 + 1] = x.y;
      tile[r][c0 + j4 * 4 + 2] = x.z;
      tile[r][c0 + j4 * 4 + 3] = x.w;
    }
    __syncthreads();
    const int d_l = tid & 63;
    const int kc0 = (tid >> 6) * 2;  // 0,2,4,6
#pragma unroll
    for (int k2 = 0; k2 < 2; ++k2) {
      const int kc = kc0 + k2;
      bf16x8 wv;
#pragma unroll
      for (int j = 0; j < 8; ++j) wv[j] = (bf16_t)tile[kc * 8 + j][d_l];
      *(bf16x8*)&VT[((size_t)(T * 8 + kc) * 128 + d0 + d_l) * 8] = wv;
    }
  } else {
    // K convert: one 16B chunk per thread
    const int base = (b - 256) * 2048 + tid * 8;   // flat over 8192*128
    const int row = base >> 7;
    const int c = (base >> 3) & 15;
    const int T = row >> 6;
    const int r = row & 63;
    float4 a = *(const float4*)&K[base];
    float4 cc = *(const float4*)&K[base + 4];
    bf16x8 f;
    f[0] = (bf16_t)a.x; f[1] = (bf16_t)a.y; f[2] = (bf16_t)a.z; f[3] = (bf16_t)a.w;
    f[4] = (bf16_t)cc.x; f[5] = (bf16_t)cc.y; f[6] = (bf16_t)cc.z; f[7] = (bf16_t)cc.w;
    *(bf16x8*)&Kb[((size_t)(T * 16 + c) * 64 + r) * 8] = f;
  }
}

// ---------------- main flash-attention kernel ----------------
// R12 = R9 + counted-vmcnt barriers (T4). BM=256, 8 waves, wave w owns
// 32 q-rows x all keys x all d; cross-tile pipeline (QK(it) -> PV(it-1)
// interleaved with exp(it); permlane32_swap exchange; P in registers).
// NEW: K prefetched TWO tiles ahead into kt3[3]; V one ahead into vt3[3];
// the per-iteration barrier is s_waitcnt vmcnt(4) (the 4 loads just issued
// stay in flight across the barrier) instead of __syncthreads' vmcnt(0)
// drain -- the DMA round-trip is no longer exposed on the barrier path.
// Tail peels with vmcnt(2)/vmcnt(0) as the prefetch stream runs dry.
__global__ __launch_bounds__(THREADS, 2) void fattn_kernel(
    const float* __restrict__ Q, const bf16_t* __restrict__ Kb,
    const bf16_t* __restrict__ VT, float* __restrict__ Opart,
    float* __restrict__ Lpart, int kshift, int nit) {
  __shared__ __align__(16) bf16_t kt3[3][16][64][8];  // 48 KB [buf][d-chunk][key][8]
  __shared__ __align__(16) bf16_t vt3[3][8][128][8];  // 48 KB [buf][key-chunk][d][8]

  const int tid = (int)threadIdx.x;
  const int lane = tid & 63;
  const int w = tid >> 6;          // q-group 0..7
  const int h = lane >> 5;
  const int n32 = lane & 31;

  const int qt = (int)blockIdx.x >> kshift;
  const int sp = (int)blockIdx.x & ((1 << kshift) - 1);
  const int qbase = qt * BM;
  const int tile0 = sp * nit;          // first 64-key tile index

  const float SC2 = 0.08838834764831845f * 1.4426950408889634f; // (1/sqrt(128))*log2e

  // Q B-frags (n = n32 = q-row, k-dim = d), pre-scaled
  bf16x8 qf[8];
  {
    const float* qp = Q + (size_t)(qbase + w * 32 + n32) * HD + h * 8;
#pragma unroll
    for (int kk = 0; kk < 8; ++kk) {
      float4 a = *(const float4*)(qp + kk * 16);
      float4 b = *(const float4*)(qp + kk * 16 + 4);
      bf16x8 f;
      f[0] = (bf16_t)(a.x * SC2); f[1] = (bf16_t)(a.y * SC2);
      f[2] = (bf16_t)(a.z * SC2); f[3] = (bf16_t)(a.w * SC2);
      f[4] = (bf16_t)(b.x * SC2); f[5] = (bf16_t)(b.y * SC2);
      f[6] = (bf16_t)(b.z * SC2); f[7] = (bf16_t)(b.w * SC2);
      qf[kk] = f;
    }
  }

  f32x16 o_acc[4];   // O[32q x 128d]
#pragma unroll
  for (int i = 0; i < 4; ++i)
#pragma unroll
    for (int e = 0; e < 16; ++e) o_acc[i][e] = 0.f;
  float l_acc = 0.f;

  bf16x8 paA[4], paB[4];   // P A-frags for one 64-key tile (alternating)

  const int rr0 = w * 2;   // DMA region indices rr0, rr0+1 (8 waves x 2 = 16)
  char* const ktB = (char*)&kt3[0][0][0][0];
  char* const vtB = (char*)&vt3[0][0][0][0];

#define DMA_K(TILE, BUF)                                                   \
  _Pragma("unroll")                                                        \
  for (int t = 0; t < 2; ++t) {                                            \
    const int rr = rr0 + t;                                                \
    load_lds16(Kb + ((size_t)((TILE) * 16 + rr) * 64 + lane) * 8,          \
               ktB + (BUF) * 16384 + rr * 1024);                           \
  }
#define DMA_V(TILE, BUF)                                                   \
  _Pragma("unroll")                                                        \
  for (int t = 0; t < 2; ++t) {                                            \
    const int rr = rr0 + t;                                                \
    load_lds16(VT + ((size_t)((TILE) * 8 + (rr >> 1)) * 128 + (rr & 1) * 64 + lane) * 8, \
               vtB + (BUF) * 16384 + rr * 1024);                           \
  }

// exp -> pack -> permlane32_swap exchange -> ONE PV A-frag (16 keys).
#define EXPPACK1(SACC, KK2, PDST_EXPR)                                     \
  {                                                                        \
    float pf[8];                                                           \
    _Pragma("unroll")                                                      \
    for (int j = 0; j < 8; ++j) pf[j] = exp2_fast((SACC)[8 * (KK2) + j]);  \
    l_acc += ((pf[0] + pf[1]) + (pf[2] + pf[3])) +                         \
             ((pf[4] + pf[5]) + (pf[6] + pf[7]));                          \
    bf16x2 p0, p1, p2, p3;                                                 \
    p0[0] = (bf16_t)pf[0]; p0[1] = (bf16_t)pf[1];                          \
    p1[0] = (bf16_t)pf[2]; p1[1] = (bf16_t)pf[3];                          \
    p2[0] = (bf16_t)pf[4]; p2[1] = (bf16_t)pf[5];                          \
    p3[0] = (bf16_t)pf[6]; p3[1] = (bf16_t)pf[7];                          \
    unsigned int sA = __builtin_bit_cast(unsigned int, p0);                \
    unsigned int sB = __builtin_bit_cast(unsigned int, p1);                \
    unsigned int sC = __builtin_bit_cast(unsigned int, p2);                \
    unsigned int sD = __builtin_bit_cast(unsigned int, p3);                \
    permswap32(sA, sC);                                                    \
    permswap32(sB, sD);                                                    \
    u32x4 fv;                                                              \
    fv[0] = sA; fv[1] = sB; fv[2] = sC; fv[3] = sD;                        \
    (PDST_EXPR) = __builtin_bit_cast(bf16x8, fv);                          \
  }

// one PV chunk: 16 keys (frag PP[C]) x all 128 d -> 4 MFMA, reads vt3[vp]
#define PVC(PP, C)                                                         \
  _Pragma("unroll")                                                        \
  for (int ot = 0; ot < 4; ++ot) {                                         \
    bf16x8 vb = *(const bf16x8*)(vtB + vp * 16384 + ((C) * 2 + h) * 2048 + \
                                 (ot * 32 + n32) * 16);                    \
    o_acc[ot] = __builtin_amdgcn_mfma_f32_32x32x16_bf16(PP[C], vb, o_acc[ot], 0, 0, 0); \
  }

// pipelined body: DMA K(two ahead)/V(one ahead); QK^T(it) from kt3[kc]
// (chains interleaved); 4x [PV(it-1) chunk || exp(it) chunk]; counted
// barrier; rotate buffers. DOK/DOV/VMN are literals.
#define FBODY(PPREV, PCUR, DOK, DOV, VMN)                                  \
  {                                                                        \
    if (DOK) { DMA_K(ktile, kd) }                                          \
    if (DOV) { DMA_V(vtile, vd) }                                          \
    f32x16 sacc0, sacc1;                                                   \
    _Pragma("unroll")                                                      \
    for (int e = 0; e < 16; ++e) { sacc0[e] = 0.f; sacc1[e] = 0.f; }       \
    _Pragma("unroll")                                                      \
    for (int kk = 0; kk < 8; ++kk) {                                       \
      bf16x8 af0 = *(const bf16x8*)(ktB + kc * 16384 + (2 * kk + h) * 1024 + n32 * 16); \
      sacc0 = __builtin_amdgcn_mfma_f32_32x32x16_bf16(af0, qf[kk], sacc0, 0, 0, 0); \
      bf16x8 af1 = *(const bf16x8*)(ktB + kc * 16384 + (2 * kk + h) * 1024 + (32 + n32) * 16); \
      sacc1 = __builtin_amdgcn_mfma_f32_32x32x16_bf16(af1, qf[kk], sacc1, 0, 0, 0); \
    }                                                                      \
    PVC(PPREV, 0) EXPPACK1(sacc0, 0, PCUR[0])                              \
    PVC(PPREV, 1) EXPPACK1(sacc0, 1, PCUR[1])                              \
    PVC(PPREV, 2) EXPPACK1(sacc1, 0, PCUR[2])                              \
    PVC(PPREV, 3) EXPPACK1(sacc1, 1, PCUR[3])                              \
    BARRIER(VMN);                                                          \
    kc = (kc + 1 == 3) ? 0 : kc + 1;                                       \
    kd = (kd + 1 == 3) ? 0 : kd + 1;                                       \
    vp = (vp + 1 == 3) ? 0 : vp + 1;                                       \
    vd = (vd + 1 == 3) ? 0 : vd + 1;                                       \
    ++ktile; ++vtile;                                                      \
  }

  // ---- prologue: K(0)->kt0, V(0)->vt0, K(1)->kt1; drain to K(1) in flight
  DMA_K(tile0, 0)
  DMA_V(tile0, 0)
  DMA_K(tile0 + 1, 1)
  BARRIER(2);   // Q loads + K(0) + V(0) landed; K(1)'s 2 ops in flight

  // ---- peel it=0: issue K(2)->kt2, V(1)->vt1; QK(0); exp -> paA ----
  {
    DMA_K(tile0 + 2, 2)
    DMA_V(tile0 + 1, 1)
    f32x16 sacc0, sacc1;
#pragma unroll
    for (int e = 0; e < 16; ++e) { sacc0[e] = 0.f; sacc1[e] = 0.f; }
#pragma unroll
    for (int kk = 0; kk < 8; ++kk) {
      bf16x8 af0 = *(const bf16x8*)(ktB + (2 * kk + h) * 1024 + n32 * 16);
      sacc0 = __builtin_amdgcn_mfma_f32_32x32x16_bf16(af0, qf[kk], sacc0, 0, 0, 0);
      bf16x8 af1 = *(const bf16x8*)(ktB + (2 * kk + h) * 1024 + (32 + n32) * 16);
      sacc1 = __builtin_amdgcn_mfma_f32_32x32x16_bf16(af1, qf[kk], sacc1, 0, 0, 0);
    }
    EXPPACK1(sacc0, 0, paA[0])
    EXPPACK1(sacc0, 1, paA[1])
    EXPPACK1(sacc1, 0, paA[2])
    EXPPACK1(sacc1, 1, paA[3])
    BARRIER(4);   // K(1) landed; {K(2), V(1)} in flight
  }

  int kc = 1, kd = 0;              // kt read buf (it%3), kt DMA buf ((it+2)%3)
  int vp = 0, vd = 2;              // vt PV buf ((it-1)%3), vt DMA buf ((it+1)%3)
  int ktile = tile0 + 3;           // K DMA tile (it+2)
  int vtile = tile0 + 2;           // V DMA tile (it+1)

  // main: it = 1 .. nit-4 in pairs (paA/paB alternation), then peel
  // it = nit-3 (full issue), nit-2 (V only), nit-1 (no issue).  nit even.
  for (int it = 1; it <= nit - 4; it += 2) {
    FBODY(paA, paB, 1, 1, 4)
    FBODY(paB, paA, 1, 1, 4)
  }
  FBODY(paA, paB, 1, 1, 4)   // it = nit-3 (odd)
  FBODY(paB, paA, 0, 1, 2)   // it = nit-2 (even): only V(nit-1) in flight
  FBODY(paA, paB, 0, 0, 0)   // it = nit-1 (odd): full drain for tail

  // ---- tail: PV(nit-1) using paB, vt3[vp] (vp == (nit-1)%3) ----
  PVC(paB, 0)
  PVC(paB, 1)
  PVC(paB, 2)
  PVC(paB, 3)

#undef FBODY
#undef PVC
#undef EXPPACK1
#undef DMA_K
#undef DMA_V

  // ---- epilogue: O block store + L (all intra-wave) ----
  {
    float* op = Opart + ((size_t)sp * SEQ + qbase + w * 32) * HD;
#pragma unroll
    for (int ot = 0; ot < 4; ++ot)
#pragma unroll
      for (int reg = 0; reg < 16; ++reg) {
        const int row = (reg & 3) + 8 * (reg >> 2) + 4 * h;
        op[row * HD + ot * 32 + n32] = o_acc[ot][reg];
      }
    float l = l_acc + __shfl_xor(l_acc, 32);   // combine the two key-halves
    if (lane < 32)
      Lpart[(size_t)sp * SEQ + qbase + w * 32 + n32] = l;
  }
}

// ---------------- combine: out = sum_s O_s / sum_s l_s ----------------
__global__ __launch_bounds__(256) void combine_kernel(const float* __restrict__ Opart,
                                                      const float* __restrict__ Lpart,
                                                      float* __restrict__ out, int ksplit) {
  const int tid = (int)threadIdx.x;
  const int row = (int)blockIdx.x * 8 + (tid >> 5);
  const int c0 = (tid & 31) * 4;
  float lsum = 0.f;
  for (int s = 0; s < ksplit; ++s) lsum += Lpart[(size_t)s * SEQ + row];
  f32x4 acc;
#pragma unroll
  for (int e = 0; e < 4; ++e) acc[e] = 0.f;
  for (int s = 0; s < ksplit; ++s) {
    f32x4 o = *(const f32x4*)&Opart[((size_t)s * SEQ + row) * HD + c0];
#pragma unroll
    for (int e = 0; e < 4; ++e) acc[e] += o[e];
  }
  const float inv = 1.0f / lsum;
  f32x4 res;
#pragma unroll
  for (int e = 0; e < 4; ++e) res[e] = acc[e] * inv;
  *(f32x4*)&out[(size_t)row * HD + c0] = res;
}

extern "C" void kernel_launch(void* const* d_in, const int* in_sizes, int n_in,
                              void* d_out, int out_size, void* d_ws, size_t ws_size,
                              hipStream_t stream) {
  const float* Q = (const float*)d_in[0];
  const float* K = (const float*)d_in[1];
  const float* V = (const float*)d_in[2];
  float* out = (float*)d_out;

  int ksplit = 8, kshift = 3;
  while (ksplit > 1) {
    size_t need = (size_t)ksplit * SEQ * HD * 4
                + (size_t)ksplit * SEQ * 4
                + (size_t)SEQ * HD * 2 * 2;
    if (need <= ws_size) break;
    ksplit >>= 1; kshift--;
  }

  char* ws = (char*)d_ws;
  float* Opart = (float*)ws;
  float* Lpart = (float*)(ws + (size_t)ksplit * SEQ * HD * 4);
  bf16_t* Kb = (bf16_t*)(ws + (size_t)ksplit * SEQ * HD * 4 + (size_t)ksplit * SEQ * 4);
  bf16_t* VT = Kb + (size_t)SEQ * HD;

  const int nit = SEQ / (ksplit * BN);

  prep_kernel<<<768, 256, 0, stream>>>(K, V, Kb, VT);
  fattn_kernel<<<NQT * ksplit, THREADS, 0, stream>>>(Q, Kb, VT, Opart, Lpart, kshift, nit);
  combine_kernel<<<SEQ / 8, 256, 0, stream>>>(Opart, Lpart, out, ksplit);
}